// Round 20
// baseline (160.547 us; speedup 1.0000x reference)
//
#include <hip/hip_runtime.h>

typedef __attribute__((ext_vector_type(8))) short short8;
typedef __attribute__((ext_vector_type(4))) float f32x4;
typedef __attribute__((ext_vector_type(16))) float f32x16;

#define DEV static __device__ __forceinline__

DEV unsigned short f2bf(float f) {
  unsigned int u = __float_as_uint(f);
  u += 0x7fff + ((u >> 16) & 1);   // RNE
  return (unsigned short)(u >> 16);
}

DEV unsigned int cvtpk(float lo, float hi) {   // packed f32x2 -> bf16x2 (RNE)
  unsigned int r;
  asm("v_cvt_pk_bf16_f32 %0, %1, %2" : "=v"(r) : "v"(lo), "v"(hi));
  return r;
}

DEV float max3f(float a, float b, float c) {
  float r;
  asm("v_max3_f32 %0, %1, %2, %3" : "=v"(r) : "v"(a), "v"(b), "v"(c));
  return r;
}

DEV f32x4 mfma16(short8 a, short8 b, f32x4 c) {
  return __builtin_amdgcn_mfma_f32_16x16x32_bf16(a, b, c, 0, 0, 0);
}

DEV f32x16 mfma32(short8 a, short8 b, f32x16 c) {
  return __builtin_amdgcn_mfma_f32_32x32x16_bf16(a, b, c, 0, 0, 0);
}

DEV void gl_lds16(const void* g, void* l) {
  __builtin_amdgcn_global_load_lds((const __attribute__((address_space(1))) void*)g,
                                   (__attribute__((address_space(3))) void*)l, 16, 0, 0);
}

// ---------------------------------------------------------------------------
// Convert Wq / Wk / Wv fp32 -> bf16 (wqb 1024x1024; wkvb 512x1024, k then v)
// ---------------------------------------------------------------------------
__global__ __launch_bounds__(256) void cvtB_kernel(const float* __restrict__ Wq,
                                                   const float* __restrict__ Wk,
                                                   const float* __restrict__ Wv,
                                                   unsigned short* __restrict__ wqb,
                                                   unsigned short* __restrict__ wkvb) {
  int id = blockIdx.x * 256 + threadIdx.x;
  int e = id * 4;
  float4 v;
  unsigned short* d;
  if (e < 1048576)      { v = *(const float4*)(Wq + e);             d = wqb + e; }
  else if (e < 1310720) { v = *(const float4*)(Wk + (e - 1048576)); d = wkvb + (e - 1048576); }
  else                  { v = *(const float4*)(Wv + (e - 1310720)); d = wkvb + 262144 + (e - 1310720); }
  uint2 pk;
  pk.x = cvtpk(v.x, v.y);
  pk.y = cvtpk(v.z, v.w);
  *(uint2*)d = pk;
}

// ---------------------------------------------------------------------------
// Wrp = Wr @ Wo  (2 x 1024)
// ---------------------------------------------------------------------------
__global__ __launch_bounds__(256) void wrp_partial(const float* __restrict__ Wr,
                                                   const float* __restrict__ Wo,
                                                   float* __restrict__ part) {
  int blk = blockIdx.x;
  int tid = threadIdx.x;
  float a0[4] = {0.f,0.f,0.f,0.f};
  float a1[4] = {0.f,0.f,0.f,0.f};
  int e0 = blk * 64;
  for (int e = e0; e < e0 + 64; e++) {
    float w0 = Wr[e];
    float w1 = Wr[1024 + e];
    #pragma unroll
    for (int j4 = 0; j4 < 4; j4++) {
      float wo = Wo[(size_t)e * 1024 + j4 * 256 + tid];
      a0[j4] += w0 * wo;
      a1[j4] += w1 * wo;
    }
  }
  #pragma unroll
  for (int j4 = 0; j4 < 4; j4++) {
    part[blk * 2048 + 0    + j4 * 256 + tid] = a0[j4];
    part[blk * 2048 + 1024 + j4 * 256 + tid] = a1[j4];
  }
}

__global__ __launch_bounds__(256) void wrp_reduce(const float* __restrict__ part,
                                                  float* __restrict__ Wrp) {
  int id = blockIdx.x * 256 + threadIdx.x;
  float s = 0.f;
  #pragma unroll
  for (int blk = 0; blk < 16; blk++) s += part[blk * 2048 + id];
  Wrp[id] = s;
}

// ---------------------------------------------------------------------------
// KV projection v10: v6 compute structure, DEPTH-2 (80KB LDS -> 2 blocks/CU).
// Drain-0 at step end; the co-resident block covers the drain (m114).
// Both outputs row-major (B,KV,K,D); V^T built by vtr kernel.
// ---------------------------------------------------------------------------
__global__ __launch_bounds__(512, 2) void gemm_kv(const float* __restrict__ A,
                                                  const unsigned short* __restrict__ Bb,
                                                  unsigned short* __restrict__ ok,
                                                  unsigned short* __restrict__ vrm) {
  __shared__ unsigned short Asl[2][4096];    // [128][32] bf16, 8KB each
  __shared__ unsigned short Bsl[2][16384];   // [512][32] bf16, 32KB each

  int bid = blockIdx.x;
  int sw = (bid & 7) * 32 + (bid >> 3);      // XCD swizzle (256 = 8*32)
  int m0 = sw * 128;

  int tid = threadIdx.x;
  int w = tid >> 6, l = tid & 63;
  int l4 = l >> 4, l15 = l & 15;

  int arow = tid >> 2, ac = tid & 3;
  const float* ga = A + (size_t)(m0 + arow) * 1024 + ac * 8;
  int awb = arow * 64 + ((ac ^ ((arow >> 1) & 3)) * 16);

  const unsigned short* gbB = Bb + (size_t)(tid >> 2) * 1024
                                 + (((tid & 3) ^ ((tid >> 3) & 3)) * 8);

  int fsw = (l4 ^ ((l15 >> 1) & 3)) * 16;
  int aoff = l15 * 64 + fsw;                   // + i*1024
  int boff = (w * 64 + l15) * 64 + fsw;        // + j*1024

  f32x4 acc[8][4];
  #pragma unroll
  for (int i = 0; i < 8; i++)
    #pragma unroll
    for (int j = 0; j < 4; j++) acc[i][j] = (f32x4)(0.f);

  float4 aX, aY;

  #define LOADA(T)                                                          \
    { const float* gA = ga + (T) * 32;                                      \
      aX = *(const float4*)(gA);                                            \
      aY = *(const float4*)(gA + 4); }

  #define STAGEB(SB, T)                                                     \
    { const unsigned short* b0p = gbB + (T) * 32;                           \
      gl_lds16(b0p,          (char*)Bsl[SB] + tid * 16);                    \
      gl_lds16(b0p + 131072, (char*)Bsl[SB] + 8192  + tid * 16);            \
      gl_lds16(b0p + 262144, (char*)Bsl[SB] + 16384 + tid * 16);            \
      gl_lds16(b0p + 393216, (char*)Bsl[SB] + 24576 + tid * 16); }

  #define WRITEA(WB)                                                        \
    { union { short8 s; unsigned int u[4]; } af;                            \
      af.u[0] = cvtpk(aX.x, aX.y); af.u[1] = cvtpk(aX.z, aX.w);             \
      af.u[2] = cvtpk(aY.x, aY.y); af.u[3] = cvtpk(aY.z, aY.w);             \
      *(short8*)((char*)Asl[WB] + awb) = af.s; }

  #define COMPUTE(CB)                                                       \
    { const char* Ab = (const char*)Asl[CB];                                \
      const char* Bf = (const char*)Bsl[CB];                                \
      short8 bfr[4];                                                        \
      _Pragma("unroll")                                                     \
      for (int j = 0; j < 4; j++)                                           \
        bfr[j] = *(const short8*)(Bf + boff + j * 1024);                    \
      __builtin_amdgcn_s_setprio(1);                                        \
      _Pragma("unroll")                                                     \
      for (int i = 0; i < 8; i++) {                                         \
        short8 af = *(const short8*)(Ab + aoff + i * 1024);                 \
        _Pragma("unroll")                                                   \
        for (int j = 0; j < 4; j++)                                         \
          acc[i][j] = mfma16(af, bfr[j], acc[i][j]);                        \
      }                                                                     \
      __builtin_amdgcn_s_setprio(0); }

  // prologue: build buf0
  LOADA(0);
  STAGEB(0, 0);
  WRITEA(0);
  asm volatile("s_waitcnt vmcnt(0)" ::: "memory");
  asm volatile("s_waitcnt lgkmcnt(0)" ::: "memory");
  __builtin_amdgcn_s_barrier();
  __builtin_amdgcn_sched_barrier(0);

  #pragma unroll 1
  for (int t = 0; t < 32; t++) {
    int buf = t & 1;
    if (t + 1 < 32) {
      LOADA(t + 1);
      STAGEB(buf ^ 1, t + 1);          // in flight across this step's compute
    }
    COMPUTE(buf);
    if (t + 1 < 32) WRITEA(buf ^ 1);   // write-late (T14)
    asm volatile("s_waitcnt vmcnt(0)" ::: "memory");
    asm volatile("s_waitcnt lgkmcnt(0)" ::: "memory");
    __builtin_amdgcn_s_barrier();
    __builtin_amdgcn_sched_barrier(0);
  }

  #undef LOADA
  #undef STAGEB
  #undef WRITEA
  #undef COMPUTE

  // epilogue: both halves ROW-MAJOR (B,KV,K,D) — coalesced 32B chunks
  #pragma unroll
  for (int i = 0; i < 8; i++)
    #pragma unroll
    for (int j = 0; j < 4; j++) {
      int n = w * 64 + j * 16 + l15;
      int kvv = n >> 6, d = n & 63;
      #pragma unroll
      for (int r = 0; r < 4; r++) {
        int m = m0 + i * 16 + l4 * 4 + r;
        int bb = m >> 11, kk = m & 2047;
        unsigned short val = f2bf(acc[i][j][r]);
        if (kvv < 4)
          ok[((size_t)(bb * 4 + kvv) * 2048 + kk) * 64 + d] = val;           // (B,KV,K,D)
        else
          vrm[((size_t)(bb * 4 + (kvv - 4)) * 2048 + kk) * 64 + d] = val;    // (B,KV,K,D)
      }
    }
}

// ---------------------------------------------------------------------------
// V transpose: (B,KV,K,D) -> (B,KV,D,K).  64x64 LDS tiles, 2048 blocks.
// ---------------------------------------------------------------------------
__global__ __launch_bounds__(256) void vtr_kernel(const unsigned short* __restrict__ vrm,
                                                  unsigned short* __restrict__ vt) {
  __shared__ unsigned short T[64][72];
  int g = blockIdx.x >> 5;           // b*4+kvh (64)
  int kt = blockIdx.x & 31;          // k-tile of 64
  int tid = threadIdx.x;
  int r = tid >> 2, c0 = (tid & 3) * 16;

  const unsigned short* src = vrm + ((size_t)g * 2048 + kt * 64) * 64;
  *(short8*)&T[r][c0]     = *(const short8*)(src + (size_t)r * 64 + c0);
  *(short8*)&T[r][c0 + 8] = *(const short8*)(src + (size_t)r * 64 + c0 + 8);
  __syncthreads();

  int d = tid >> 2;
  unsigned short* dst = vt + (size_t)g * 131072 + (size_t)d * 2048 + kt * 64 + (tid & 3) * 16;
  short8 o0, o1;
  #pragma unroll
  for (int j = 0; j < 8; j++) {
    o0[j] = (short)T[(tid & 3) * 16 + j][d];
    o1[j] = (short)T[(tid & 3) * 16 + 8 + j][d];
  }
  *(short8*)dst = o0;
  *(short8*)(dst + 8) = o1;
}

// ---------------------------------------------------------------------------
// q projection GEMM (small): C = oq @ Wq^T, 128x128 tile, BK=32, 4-way K-split
// ---------------------------------------------------------------------------
__global__ __launch_bounds__(256) void gemm_q(const float* __restrict__ A,
                                              const unsigned short* __restrict__ Bb,
                                              float* __restrict__ of) {
  __shared__ unsigned short Asm[2][4096];
  __shared__ unsigned short Bsm[2][4096];

  int bid = blockIdx.x;
  int ksplit = bid >> 4;
  int m0 = ((bid >> 3) & 1) * 128;
  int n0 = (bid & 7) * 128;
  int t0 = ksplit * 8;
  constexpr int nt = 8;

  int tid = threadIdx.x;
  int w = tid >> 6, l = tid & 63;
  int l4 = l >> 4, l15 = l & 15;
  int wm = w >> 1, wn = w & 1;

  int ra = w * 32 + (l >> 1);
  int rx = (l >> 2) & 3;
  const float* ga = A + (size_t)(m0 + ra) * 1024 + t0 * 32 + (l & 1) * 16;
  int pw0 = (2 * (l & 1) + 0) ^ rx;
  int pw1 = (2 * (l & 1) + 1) ^ rx;
  int awb0 = ra * 64 + pw0 * 16;
  int awb1 = ra * 64 + pw1 * 16;

  int rb = w * 32 + (l >> 2);
  int cb = ((l & 3) ^ ((l >> 3) & 3)) * 8;
  const unsigned short* gb = Bb + (size_t)(n0 + rb) * 1024 + t0 * 32 + cb;

  int qsw = l4 ^ ((l15 >> 1) & 3);
  int arb = (wm * 64 + l15) * 64 + qsw * 16;
  int brb = (wn * 64 + l15) * 64 + qsw * 16;

  f32x4 acc[4][4];
  #pragma unroll
  for (int i = 0; i < 4; i++)
    #pragma unroll
    for (int j = 0; j < 4; j++) acc[i][j] = (f32x4)(0.f);

  float4 fa0, fa1, fa2, fa3;

  #define LOADA(tt)                                                        \
    { const float* gA = ga + (tt) * 32;                                    \
      fa0 = *(const float4*)(gA);                                          \
      fa1 = *(const float4*)(gA + 4);                                      \
      fa2 = *(const float4*)(gA + 8);                                      \
      fa3 = *(const float4*)(gA + 12); }

  #define WRITEA(bufi)                                                     \
    { union { short8 s; unsigned int u[4]; } t0u, t1u;                     \
      t0u.u[0] = cvtpk(fa0.x, fa0.y); t0u.u[1] = cvtpk(fa0.z, fa0.w);      \
      t0u.u[2] = cvtpk(fa1.x, fa1.y); t0u.u[3] = cvtpk(fa1.z, fa1.w);      \
      t1u.u[0] = cvtpk(fa2.x, fa2.y); t1u.u[1] = cvtpk(fa2.z, fa2.w);      \
      t1u.u[2] = cvtpk(fa3.x, fa3.y); t1u.u[3] = cvtpk(fa3.z, fa3.w);      \
      *(short8*)((char*)Asm[bufi] + awb0) = t0u.s;                         \
      *(short8*)((char*)Asm[bufi] + awb1) = t1u.s; }

  #define STAGEB(bufi, tt)                                                 \
    { char* lb = (char*)Bsm[bufi] + w * 2048;                              \
      const unsigned short* gB = gb + (tt) * 32;                           \
      gl_lds16(gB, lb);                                                    \
      gl_lds16(gB + 16384, lb + 1024); }

  LOADA(0);
  STAGEB(0, 0);
  WRITEA(0);
  __syncthreads();

  for (int t = 0; t < nt; t++) {
    int buf = t & 1;
    if (t + 1 < nt) {
      LOADA(t + 1);
      STAGEB(buf ^ 1, t + 1);
    }
    short8 af[4], bfg[4];
    #pragma unroll
    for (int i = 0; i < 4; i++)
      af[i] = *(const short8*)((char*)Asm[buf] + arb + i * 1024);
    #pragma unroll
    for (int j = 0; j < 4; j++)
      bfg[j] = *(const short8*)((char*)Bsm[buf] + brb + j * 1024);
    #pragma unroll
    for (int i = 0; i < 4; i++)
      #pragma unroll
      for (int j = 0; j < 4; j++)
        acc[i][j] = mfma16(af[i], bfg[j], acc[i][j]);
    if (t + 1 < nt) WRITEA(buf ^ 1);
    __syncthreads();
  }
  #undef LOADA
  #undef WRITEA
  #undef STAGEB

  float* o = of + (size_t)ksplit * 262144;
  #pragma unroll
  for (int i = 0; i < 4; i++)
    #pragma unroll
    for (int j = 0; j < 4; j++) {
      int n = n0 + wn * 64 + j * 16 + l15;
      #pragma unroll
      for (int r = 0; r < 4; r++) {
        int m = m0 + wm * 64 + i * 16 + l4 * 4 + r;
        o[(size_t)m * 1024 + n] = acc[i][j][r];
      }
    }
}

// ---------------------------------------------------------------------------
// Sum 4 K-split partials + RoPE + scale, write bf16 as (H, BIN, D)
// ---------------------------------------------------------------------------
__global__ __launch_bounds__(256) void rope_kernel(const float* __restrict__ qp,
                                                   const float* __restrict__ cosb,
                                                   const float* __restrict__ sinb,
                                                   unsigned short* __restrict__ qb) {
  int id = blockIdx.x * 256 + threadIdx.x;   // 262144
  int qrow = id >> 10, hd = id & 1023, hh = hd >> 6, d = hd & 63;
  int od = hh * 64 + ((d < 32) ? d + 32 : d - 32);
  float v = 0.f, o = 0.f;
  #pragma unroll
  for (int s4 = 0; s4 < 4; s4++) {
    v += qp[s4 * 262144 + qrow * 1024 + hd];
    o += qp[s4 * 262144 + qrow * 1024 + od];
  }
  if (d < 32) o = -o;
  float c = cosb[qrow * 64 + d];
  float s = sinb[qrow * 64 + d];
  float outv = (v * c + o * s) * 0.18033688011112042f;  // 0.125 * log2(e)
  qb[((size_t)hh * 256 + qrow) * 64 + d] = f2bf(outv);
}

// ---------------------------------------------------------------------------
// Flash attention v7 — r19 proven: 64 keys/barrier + depth-3 counted vmcnt.
// ---------------------------------------------------------------------------
__global__ __launch_bounds__(256) void attn_kernel(const unsigned short* __restrict__ qb,
                                                   const unsigned short* __restrict__ kb,
                                                   const unsigned short* __restrict__ vb,
                                                   const float* __restrict__ Wrp,
                                                   float* __restrict__ part) {
  __shared__ unsigned short Kt[3][4096];   // 2 subtiles x [32 keys][64 d], 8KB
  __shared__ unsigned short Vt[3][4096];   // 2 subtiles x [64 d][32 keys], 8KB

  int bid = blockIdx.x;
  int x = bid & 7, mid = (bid >> 3) & 7, top2 = bid >> 6;
  int g = mid * 8 + x;                 // b*4 + kvh
  int b = g >> 2, kvh = g & 3;
  int split = top2 >> 3;               // 0..1
  int top = top2 & 7;
  int hl = top >> 1, qh = top & 1;
  int h = kvh * 4 + hl;

  int tid = threadIdx.x;
  int w = tid >> 6, l = tid & 63;
  int q31 = l & 31, L = l >> 5;
  int qg = qh * 128 + w * 32 + q31;    // global q row

  const unsigned short* kg = kb + (size_t)(b * 4 + kvh) * 2048 * 64;
  const unsigned short* vg = vb + (size_t)(b * 4 + kvh) * 64 * 2048;

  short8 qf[4];
  #pragma unroll
  for (int c = 0; c < 4; c++)
    qf[c] = *(const short8*)&qb[((size_t)h * 256 + qg) * 64 + c * 16 + L * 8];

  f32x16 Ot[2];
  Ot[0] = (f32x16)(0.f); Ot[1] = (f32x16)(0.f);
  float m = -1e30f, lsum = 0.f;

  int ksrow = tid >> 3, kslot = tid & 7;
  const unsigned short* ksrc = kg + (size_t)ksrow * 64 + ((kslot ^ (ksrow & 7)) * 8);
  int vsrow = tid >> 2, vslot = tid & 3;
  const unsigned short* vsrc = vg + (size_t)vsrow * 2048 + ((vslot ^ ((vsrow >> 1) & 3)) * 8);

  int tb0 = split * 16;                // 64-key step base (16 steps of 64 keys)

  #define STAGE(bufi, tt)                                                       \
    { gl_lds16(ksrc + (size_t)((tt) * 2 + 0) * 2048, (char*)Kt[bufi] + tid * 16);        \
      gl_lds16(ksrc + (size_t)((tt) * 2 + 1) * 2048, (char*)Kt[bufi] + 4096 + tid * 16); \
      gl_lds16(vsrc + ((tt) * 2 + 0) * 32,           (char*)Vt[bufi] + tid * 16);        \
      gl_lds16(vsrc + ((tt) * 2 + 1) * 32,           (char*)Vt[bufi] + 4096 + tid * 16); }

  #define COMPUTE(CB)                                                           \
    _Pragma("unroll")                                                           \
    for (int sub = 0; sub < 2; sub++) {                                         \
      const char* Kb = (const char*)Kt[CB] + sub * 4096;                        \
      const char* Vb = (const char*)Vt[CB] + sub * 4096;                        \
      f32x16 st = (f32x16)(0.f);                                                \
      _Pragma("unroll")                                                         \
      for (int c = 0; c < 4; c++) {                                             \
        int row = q31;                                                          \
        int byt = row * 128 + (((c * 2 + L) ^ (row & 7)) * 16);                 \
        short8 kf = *(const short8*)(Kb + byt);                                 \
        st = mfma32(kf, qf[c], st);                                             \
      }                                                                         \
      float g0 = max3f(st[0], st[1], st[2]);                                    \
      float g1 = max3f(st[3], st[4], st[5]);                                    \
      float g2 = max3f(st[6], st[7], st[8]);                                    \
      float g3 = max3f(st[9], st[10], st[11]);                                  \
      float g4 = max3f(st[12], st[13], st[14]);                                 \
      float mx = fmaxf(max3f(g0, g1, g2), max3f(g3, g4, st[15]));               \
      mx = fmaxf(mx, __shfl_xor(mx, 32));                                       \
      if (!__all(mx <= m + 8.f)) {                                              \
        float mnew = fmaxf(m, mx);                                              \
        float corr = exp2f(m - mnew);                                           \
        lsum *= corr;                                                           \
        _Pragma("unroll")                                                       \
        for (int db = 0; db < 2; db++)                                          \
          _Pragma("unroll")                                                     \
          for (int r = 0; r < 16; r++) Ot[db][r] *= corr;                       \
        m = mnew;                                                               \
      }                                                                         \
      float p[16];                                                              \
      float ls = 0.f;                                                           \
      _Pragma("unroll")                                                         \
      for (int r = 0; r < 16; r++) {                                            \
        p[r] = exp2f(st[r] - m);                                                \
        ls += p[r];                                                             \
      }                                                                         \
      lsum += ls;                                                               \
      unsigned int pw[2][4];                                                    \
      _Pragma("unroll")                                                         \
      for (int kc = 0; kc < 2; kc++) {                                          \
        unsigned int A0 = cvtpk(p[kc * 8 + 0], p[kc * 8 + 1]);                  \
        unsigned int A1 = cvtpk(p[kc * 8 + 2], p[kc * 8 + 3]);                  \
        unsigned int B0 = cvtpk(p[kc * 8 + 4], p[kc * 8 + 5]);                  \
        unsigned int B1 = cvtpk(p[kc * 8 + 6], p[kc * 8 + 7]);                  \
        asm volatile("v_permlane32_swap_b32 %0, %1" : "+v"(A0), "+v"(B0));      \
        asm volatile("v_permlane32_swap_b32 %0, %1" : "+v"(A1), "+v"(B1));      \
        pw[kc][0] = A0; pw[kc][1] = A1; pw[kc][2] = B0; pw[kc][3] = B1;         \
      }                                                                         \
      _Pragma("unroll")                                                         \
      for (int db = 0; db < 2; db++) {                                          \
        int drow = db * 32 + q31;                                               \
        _Pragma("unroll")                                                       \
        for (int kc = 0; kc < 2; kc++) {                                        \
          int byt = drow * 64 + (((kc * 2 + L) ^ ((drow >> 1) & 3)) * 16);      \
          short8 vf = *(const short8*)(Vb + byt);                               \
          short8 pf;                                                            \
          {                                                                     \
            union { short8 s; unsigned int u[4]; } uu;                          \
            uu.u[0] = pw[kc][0]; uu.u[1] = pw[kc][1];                           \
            uu.u[2] = pw[kc][2]; uu.u[3] = pw[kc][3];                           \
            pf = uu.s;                                                          \
          }                                                                     \
          Ot[db] = mfma32(vf, pf, Ot[db]);                                      \
        }                                                                       \
      }                                                                         \
    }

  #define E8                                                                    \
    { asm volatile("s_waitcnt vmcnt(8)" ::: "memory");                          \
      __builtin_amdgcn_s_barrier();                                             \
      __builtin_amdgcn_sched_barrier(0); }

  STAGE(0, tb0 + 0);
  STAGE(1, tb0 + 1);
  asm volatile("s_waitcnt vmcnt(8)" ::: "memory");
  __builtin_amdgcn_s_barrier();
  __builtin_amdgcn_sched_barrier(0);

  #pragma unroll 1
  for (int tb = 0; tb < 12; tb += 3) {
    STAGE(2, tb0 + tb + 2); COMPUTE(0) E8;
    STAGE(0, tb0 + tb + 3); COMPUTE(1) E8;
    STAGE(1, tb0 + tb + 4); COMPUTE(2) E8;
  }
  STAGE(2, tb0 + 14); COMPUTE(0) E8;
  STAGE(0, tb0 + 15); COMPUTE(1) E8;
  COMPUTE(2)
  asm volatile("s_waitcnt vmcnt(0)" ::: "memory");
  __builtin_amdgcn_s_barrier();
  __builtin_amdgcn_sched_barrier(0);
  COMPUTE(0)

  #undef STAGE
  #undef COMPUTE
  #undef E8

  lsum += __shfl_xor(lsum, 32);

  // unnormalized Wrp fold
  float a0 = 0.f, a1 = 0.f;
  #pragma unroll
  for (int db = 0; db < 2; db++)
    #pragma unroll
    for (int rq = 0; rq < 4; rq++) {
      int dbase = db * 32 + rq * 8 + L * 4;
      float4 w0v = *(const float4*)(Wrp + h * 64 + dbase);
      float4 w1v = *(const float4*)(Wrp + 1024 + h * 64 + dbase);
      #pragma unroll
      for (int j = 0; j < 4; j++) {
        float o = Ot[db][rq * 4 + j];
        a0 += o * ((const float*)&w0v)[j];
        a1 += o * ((const float*)&w1v)[j];
      }
    }
  a0 += __shfl_xor(a0, 32);
  a1 += __shfl_xor(a1, 32);

  if (L == 0) {
    size_t base = ((((size_t)(b * 16 + h) * 256 + qg) * 2) + split) * 4;
    float4 r4;
    r4.x = m; r4.y = lsum; r4.z = a0; r4.w = a1;
    *(float4*)&part[base] = r4;
  }
}

// ---------------------------------------------------------------------------
// Combine 2 k-splits + sum heads: out[b,q,c] = br[c] + sum_h num_h/den_h
// ---------------------------------------------------------------------------
__global__ __launch_bounds__(256) void final_kernel(const float* __restrict__ part,
                                                    const float* __restrict__ br,
                                                    float* __restrict__ out) {
  int id = blockIdx.x * 256 + threadIdx.x;   // 8192
  int c = id & 1, q = (id >> 1) & 255, b = id >> 9;
  float s = br[c];
  #pragma unroll
  for (int hh = 0; hh < 16; hh++) {
    size_t base = (((size_t)(b * 16 + hh) * 256 + q) * 2) * 4;
    float4 f0 = *(const float4*)&part[base];
    float4 f1 = *(const float4*)&part[base + 4];
    float mm = fmaxf(f0.x, f1.x);
    float w0 = exp2f(f0.x - mm), w1 = exp2f(f1.x - mm);
    float den = w0 * f0.y + w1 * f1.y;
    float num = (c == 0) ? (w0 * f0.z + w1 * f1.z) : (w0 * f0.w + w1 * f1.w);
    s += num / den;
  }
  out[id] = s;
}

// ---------------------------------------------------------------------------
extern "C" void kernel_launch(void* const* d_in, const int* in_sizes, int n_in,
                              void* d_out, int out_size, void* d_ws, size_t ws_size,
                              hipStream_t stream) {
  const float* h    = (const float*)d_in[0];
  const float* fcos = (const float*)d_in[1];
  const float* fsin = (const float*)d_in[2];
  const float* Wq   = (const float*)d_in[3];
  const float* Wk   = (const float*)d_in[4];
  const float* Wv   = (const float*)d_in[5];
  const float* Wo   = (const float*)d_in[6];
  const float* oq   = (const float*)d_in[7];
  const float* Wr   = (const float*)d_in[8];
  const float* br   = (const float*)d_in[9];
  float* out = (float*)d_out;

  char* ws = (char*)d_ws;
  unsigned short* kbuf = (unsigned short*)(ws);                 // 16 MB (B,KV,K,D) bf16
  unsigned short* vbuf = (unsigned short*)(ws + 16777216);      // 16 MB (B,KV,D,K) bf16
  float* qpart         = (float*)(ws + 33554432);               // 4 MB (4,256,1024)
  unsigned short* qbf  = (unsigned short*)(ws + 37748736);      // 0.5 MB (H,BIN,D)
  float* wpart         = (float*)(ws + 38273024);               // 128 KB
  float* Wrp           = (float*)(ws + 38404096);               // 8 KB
  float* apart         = (float*)(ws + 38412288);               // 2 MB (B,H,BIN,2,4)
  unsigned short* wqb  = (unsigned short*)(ws + 42606592);      // 2 MB (1024,1024)
  unsigned short* wkvb = (unsigned short*)(ws + 44703744);      // 1 MB (512,1024)
  unsigned short* vrm  = (unsigned short*)(ws + 45752320);      // 16 MB (B,KV,K,D) bf16

  cvtB_kernel<<<dim3(1536), dim3(256), 0, stream>>>(Wq, Wk, Wv, wqb, wkvb);
  wrp_partial<<<dim3(16), dim3(256), 0, stream>>>(Wr, Wo, wpart);
  wrp_reduce<<<dim3(8), dim3(256), 0, stream>>>(wpart, Wrp);
  gemm_q<<<dim3(64), dim3(256), 0, stream>>>(oq, wqb, qpart);
  rope_kernel<<<dim3(1024), dim3(256), 0, stream>>>(qpart, fcos, fsin, qbf);
  gemm_kv<<<dim3(256), dim3(512), 0, stream>>>(h, wkvb, kbuf, vrm);
  vtr_kernel<<<dim3(2048), dim3(256), 0, stream>>>(vrm, vbuf);
  attn_kernel<<<dim3(1024), dim3(256), 0, stream>>>(qbf, kbuf, vbuf, Wrp, apart);
  final_kernel<<<dim3(32), dim3(256), 0, stream>>>(apart, br, out);
}

// Round 21
// 147.627 us; speedup vs baseline: 1.0875x; 1.0875x over previous
//
#include <hip/hip_runtime.h>

typedef __attribute__((ext_vector_type(8))) short short8;
typedef __attribute__((ext_vector_type(4))) float f32x4;
typedef __attribute__((ext_vector_type(16))) float f32x16;

#define DEV static __device__ __forceinline__

DEV unsigned short f2bf(float f) {
  unsigned int u = __float_as_uint(f);
  u += 0x7fff + ((u >> 16) & 1);   // RNE
  return (unsigned short)(u >> 16);
}

DEV unsigned int cvtpk(float lo, float hi) {   // packed f32x2 -> bf16x2 (RNE)
  unsigned int r;
  asm("v_cvt_pk_bf16_f32 %0, %1, %2" : "=v"(r) : "v"(lo), "v"(hi));
  return r;
}

DEV float max3f(float a, float b, float c) {
  float r;
  asm("v_max3_f32 %0, %1, %2, %3" : "=v"(r) : "v"(a), "v"(b), "v"(c));
  return r;
}

DEV f32x4 mfma16(short8 a, short8 b, f32x4 c) {
  return __builtin_amdgcn_mfma_f32_16x16x32_bf16(a, b, c, 0, 0, 0);
}

DEV f32x16 mfma32(short8 a, short8 b, f32x16 c) {
  return __builtin_amdgcn_mfma_f32_32x32x16_bf16(a, b, c, 0, 0, 0);
}

DEV void gl_lds16(const void* g, void* l) {
  __builtin_amdgcn_global_load_lds((const __attribute__((address_space(1))) void*)g,
                                   (__attribute__((address_space(3))) void*)l, 16, 0, 0);
}

// ---------------------------------------------------------------------------
// Convert Wq / Wk / Wv fp32 -> bf16 (wqb 1024x1024; wkvb 512x1024, k then v)
// ---------------------------------------------------------------------------
__global__ __launch_bounds__(256) void cvtB_kernel(const float* __restrict__ Wq,
                                                   const float* __restrict__ Wk,
                                                   const float* __restrict__ Wv,
                                                   unsigned short* __restrict__ wqb,
                                                   unsigned short* __restrict__ wkvb) {
  int id = blockIdx.x * 256 + threadIdx.x;
  int e = id * 4;
  float4 v;
  unsigned short* d;
  if (e < 1048576)      { v = *(const float4*)(Wq + e);             d = wqb + e; }
  else if (e < 1310720) { v = *(const float4*)(Wk + (e - 1048576)); d = wkvb + (e - 1048576); }
  else                  { v = *(const float4*)(Wv + (e - 1310720)); d = wkvb + 262144 + (e - 1310720); }
  uint2 pk;
  pk.x = cvtpk(v.x, v.y);
  pk.y = cvtpk(v.z, v.w);
  *(uint2*)d = pk;
}

// ---------------------------------------------------------------------------
// Wrp = Wr @ Wo  (2 x 1024)
// ---------------------------------------------------------------------------
__global__ __launch_bounds__(256) void wrp_partial(const float* __restrict__ Wr,
                                                   const float* __restrict__ Wo,
                                                   float* __restrict__ part) {
  int blk = blockIdx.x;
  int tid = threadIdx.x;
  float a0[4] = {0.f,0.f,0.f,0.f};
  float a1[4] = {0.f,0.f,0.f,0.f};
  int e0 = blk * 64;
  for (int e = e0; e < e0 + 64; e++) {
    float w0 = Wr[e];
    float w1 = Wr[1024 + e];
    #pragma unroll
    for (int j4 = 0; j4 < 4; j4++) {
      float wo = Wo[(size_t)e * 1024 + j4 * 256 + tid];
      a0[j4] += w0 * wo;
      a1[j4] += w1 * wo;
    }
  }
  #pragma unroll
  for (int j4 = 0; j4 < 4; j4++) {
    part[blk * 2048 + 0    + j4 * 256 + tid] = a0[j4];
    part[blk * 2048 + 1024 + j4 * 256 + tid] = a1[j4];
  }
}

__global__ __launch_bounds__(256) void wrp_reduce(const float* __restrict__ part,
                                                  float* __restrict__ Wrp) {
  int id = blockIdx.x * 256 + threadIdx.x;
  float s = 0.f;
  #pragma unroll
  for (int blk = 0; blk < 16; blk++) s += part[blk * 2048 + id];
  Wrp[id] = s;
}

// ---------------------------------------------------------------------------
// KV projection (r16/r19 proven): v6 compute structure, BOTH outputs
// row-major (B,KV,K,D) — coalesced 32B-chunk stores. V^T built by vtr.
// ---------------------------------------------------------------------------
__global__ __launch_bounds__(512, 2) void gemm_kv(const float* __restrict__ A,
                                                  const unsigned short* __restrict__ Bb,
                                                  unsigned short* __restrict__ ok,
                                                  unsigned short* __restrict__ vrm) {
  __shared__ unsigned short Asl[3][4096];    // [128][32] bf16, 8KB each
  __shared__ unsigned short Bsl[3][16384];   // [512][32] bf16, 32KB each

  int bid = blockIdx.x;
  int sw = (bid & 7) * 32 + (bid >> 3);      // XCD swizzle (256 = 8*32)
  int m0 = sw * 128;

  int tid = threadIdx.x;
  int w = tid >> 6, l = tid & 63;
  int l4 = l >> 4, l15 = l & 15;

  int arow = tid >> 2, ac = tid & 3;
  const float* ga = A + (size_t)(m0 + arow) * 1024 + ac * 8;
  int awb = arow * 64 + ((ac ^ ((arow >> 1) & 3)) * 16);

  const unsigned short* gbB = Bb + (size_t)(tid >> 2) * 1024
                                 + (((tid & 3) ^ ((tid >> 3) & 3)) * 8);

  int fsw = (l4 ^ ((l15 >> 1) & 3)) * 16;
  int aoff = l15 * 64 + fsw;                   // + i*1024
  int boff = (w * 64 + l15) * 64 + fsw;        // + j*1024

  f32x4 acc[8][4];
  #pragma unroll
  for (int i = 0; i < 8; i++)
    #pragma unroll
    for (int j = 0; j < 4; j++) acc[i][j] = (f32x4)(0.f);

  float4 aXx, aXy, aYx, aYy;

  #define LOADA(T, RX, RY)                                                  \
    { const float* gA = ga + (T) * 32;                                      \
      RX = *(const float4*)(gA);                                            \
      RY = *(const float4*)(gA + 4); }

  #define STAGEB(SB, T)                                                     \
    { const unsigned short* b0p = gbB + (T) * 32;                           \
      gl_lds16(b0p,          (char*)Bsl[SB] + tid * 16);                    \
      gl_lds16(b0p + 131072, (char*)Bsl[SB] + 8192  + tid * 16);            \
      gl_lds16(b0p + 262144, (char*)Bsl[SB] + 16384 + tid * 16);            \
      gl_lds16(b0p + 393216, (char*)Bsl[SB] + 24576 + tid * 16); }

  #define WRITEA(WB, RX, RY)                                                \
    { union { short8 s; unsigned int u[4]; } af;                            \
      af.u[0] = cvtpk(RX.x, RX.y); af.u[1] = cvtpk(RX.z, RX.w);             \
      af.u[2] = cvtpk(RY.x, RY.y); af.u[3] = cvtpk(RY.z, RY.w);             \
      *(short8*)((char*)Asl[WB] + awb) = af.s; }

  #define COMPUTE(CB)                                                       \
    { const char* Ab = (const char*)Asl[CB];                                \
      const char* Bf = (const char*)Bsl[CB];                                \
      short8 bfr[4];                                                        \
      _Pragma("unroll")                                                     \
      for (int j = 0; j < 4; j++)                                           \
        bfr[j] = *(const short8*)(Bf + boff + j * 1024);                    \
      __builtin_amdgcn_s_setprio(1);                                        \
      _Pragma("unroll")                                                     \
      for (int i = 0; i < 8; i++) {                                         \
        short8 af = *(const short8*)(Ab + aoff + i * 1024);                 \
        _Pragma("unroll")                                                   \
        for (int j = 0; j < 4; j++)                                         \
          acc[i][j] = mfma16(af, bfr[j], acc[i][j]);                        \
      }                                                                     \
      __builtin_amdgcn_s_setprio(0); }

  #define ENDSTEP                                                           \
    { asm volatile("s_waitcnt vmcnt(6)" ::: "memory");                      \
      asm volatile("s_waitcnt lgkmcnt(0)" ::: "memory");                    \
      __builtin_amdgcn_s_barrier();                                         \
      __builtin_amdgcn_sched_barrier(0); }

  LOADA(0, aXx, aXy);
  STAGEB(0, 0);
  WRITEA(0, aXx, aXy);
  LOADA(1, aXx, aXy);
  STAGEB(1, 1);
  asm volatile("s_waitcnt vmcnt(6)" ::: "memory");
  asm volatile("s_waitcnt lgkmcnt(0)" ::: "memory");
  __builtin_amdgcn_s_barrier();
  __builtin_amdgcn_sched_barrier(0);

  #define STEPE(T, CB, WB, SB)                                              \
    { LOADA((T) + 2, aYx, aYy); STAGEB(SB, (T) + 2);                        \
      COMPUTE(CB); WRITEA(WB, aXx, aXy); ENDSTEP }
  #define STEPO(T, CB, WB, SB)                                              \
    { LOADA((T) + 2, aXx, aXy); STAGEB(SB, (T) + 2);                        \
      COMPUTE(CB); WRITEA(WB, aYx, aYy); ENDSTEP }

  #pragma unroll 1
  for (int tb = 0; tb < 30; tb += 6) {
    STEPE(tb + 0, 0, 1, 2);
    STEPO(tb + 1, 1, 2, 0);
    STEPE(tb + 2, 2, 0, 1);
    STEPO(tb + 3, 0, 1, 2);
    STEPE(tb + 4, 1, 2, 0);
    STEPO(tb + 5, 2, 0, 1);
  }
  COMPUTE(0);
  WRITEA(1, aXx, aXy);
  asm volatile("s_waitcnt vmcnt(0)" ::: "memory");
  asm volatile("s_waitcnt lgkmcnt(0)" ::: "memory");
  __builtin_amdgcn_s_barrier();
  __builtin_amdgcn_sched_barrier(0);
  COMPUTE(1);

  #undef LOADA
  #undef STAGEB
  #undef WRITEA
  #undef COMPUTE
  #undef ENDSTEP
  #undef STEPE
  #undef STEPO

  // epilogue: both halves ROW-MAJOR (B,KV,K,D) — coalesced 32B chunks
  #pragma unroll
  for (int i = 0; i < 8; i++)
    #pragma unroll
    for (int j = 0; j < 4; j++) {
      int n = w * 64 + j * 16 + l15;
      int kvv = n >> 6, d = n & 63;
      #pragma unroll
      for (int r = 0; r < 4; r++) {
        int m = m0 + i * 16 + l4 * 4 + r;
        int bb = m >> 11, kk = m & 2047;
        unsigned short val = f2bf(acc[i][j][r]);
        if (kvv < 4)
          ok[((size_t)(bb * 4 + kvv) * 2048 + kk) * 64 + d] = val;           // (B,KV,K,D)
        else
          vrm[((size_t)(bb * 4 + (kvv - 4)) * 2048 + kk) * 64 + d] = val;    // (B,KV,K,D)
      }
    }
}

// ---------------------------------------------------------------------------
// V transpose: (B,KV,K,D) -> (B,KV,D,K).  64x64 LDS tiles, 2048 blocks.
// ---------------------------------------------------------------------------
__global__ __launch_bounds__(256) void vtr_kernel(const unsigned short* __restrict__ vrm,
                                                  unsigned short* __restrict__ vt) {
  __shared__ unsigned short T[64][72];
  int g = blockIdx.x >> 5;           // b*4+kvh (64)
  int kt = blockIdx.x & 31;          // k-tile of 64
  int tid = threadIdx.x;
  int r = tid >> 2, c0 = (tid & 3) * 16;

  const unsigned short* src = vrm + ((size_t)g * 2048 + kt * 64) * 64;
  *(short8*)&T[r][c0]     = *(const short8*)(src + (size_t)r * 64 + c0);
  *(short8*)&T[r][c0 + 8] = *(const short8*)(src + (size_t)r * 64 + c0 + 8);
  __syncthreads();

  int d = tid >> 2;
  unsigned short* dst = vt + (size_t)g * 131072 + (size_t)d * 2048 + kt * 64 + (tid & 3) * 16;
  short8 o0, o1;
  #pragma unroll
  for (int j = 0; j < 8; j++) {
    o0[j] = (short)T[(tid & 3) * 16 + j][d];
    o1[j] = (short)T[(tid & 3) * 16 + 8 + j][d];
  }
  *(short8*)dst = o0;
  *(short8*)(dst + 8) = o1;
}

// ---------------------------------------------------------------------------
// q projection GEMM (small): C = oq @ Wq^T, 128x128 tile, BK=32, 4-way K-split
// ---------------------------------------------------------------------------
__global__ __launch_bounds__(256) void gemm_q(const float* __restrict__ A,
                                              const unsigned short* __restrict__ Bb,
                                              float* __restrict__ of) {
  __shared__ unsigned short Asm[2][4096];
  __shared__ unsigned short Bsm[2][4096];

  int bid = blockIdx.x;
  int ksplit = bid >> 4;
  int m0 = ((bid >> 3) & 1) * 128;
  int n0 = (bid & 7) * 128;
  int t0 = ksplit * 8;
  constexpr int nt = 8;

  int tid = threadIdx.x;
  int w = tid >> 6, l = tid & 63;
  int l4 = l >> 4, l15 = l & 15;
  int wm = w >> 1, wn = w & 1;

  int ra = w * 32 + (l >> 1);
  int rx = (l >> 2) & 3;
  const float* ga = A + (size_t)(m0 + ra) * 1024 + t0 * 32 + (l & 1) * 16;
  int pw0 = (2 * (l & 1) + 0) ^ rx;
  int pw1 = (2 * (l & 1) + 1) ^ rx;
  int awb0 = ra * 64 + pw0 * 16;
  int awb1 = ra * 64 + pw1 * 16;

  int rb = w * 32 + (l >> 2);
  int cb = ((l & 3) ^ ((l >> 3) & 3)) * 8;
  const unsigned short* gb = Bb + (size_t)(n0 + rb) * 1024 + t0 * 32 + cb;

  int qsw = l4 ^ ((l15 >> 1) & 3);
  int arb = (wm * 64 + l15) * 64 + qsw * 16;
  int brb = (wn * 64 + l15) * 64 + qsw * 16;

  f32x4 acc[4][4];
  #pragma unroll
  for (int i = 0; i < 4; i++)
    #pragma unroll
    for (int j = 0; j < 4; j++) acc[i][j] = (f32x4)(0.f);

  float4 fa0, fa1, fa2, fa3;

  #define LOADA(tt)                                                        \
    { const float* gA = ga + (tt) * 32;                                    \
      fa0 = *(const float4*)(gA);                                          \
      fa1 = *(const float4*)(gA + 4);                                      \
      fa2 = *(const float4*)(gA + 8);                                      \
      fa3 = *(const float4*)(gA + 12); }

  #define WRITEA(bufi)                                                     \
    { union { short8 s; unsigned int u[4]; } t0u, t1u;                     \
      t0u.u[0] = cvtpk(fa0.x, fa0.y); t0u.u[1] = cvtpk(fa0.z, fa0.w);      \
      t0u.u[2] = cvtpk(fa1.x, fa1.y); t0u.u[3] = cvtpk(fa1.z, fa1.w);      \
      t1u.u[0] = cvtpk(fa2.x, fa2.y); t1u.u[1] = cvtpk(fa2.z, fa2.w);      \
      t1u.u[2] = cvtpk(fa3.x, fa3.y); t1u.u[3] = cvtpk(fa3.z, fa3.w);      \
      *(short8*)((char*)Asm[bufi] + awb0) = t0u.s;                         \
      *(short8*)((char*)Asm[bufi] + awb1) = t1u.s; }

  #define STAGEB(bufi, tt)                                                 \
    { char* lb = (char*)Bsm[bufi] + w * 2048;                              \
      const unsigned short* gB = gb + (tt) * 32;                           \
      gl_lds16(gB, lb);                                                    \
      gl_lds16(gB + 16384, lb + 1024); }

  LOADA(0);
  STAGEB(0, 0);
  WRITEA(0);
  __syncthreads();

  for (int t = 0; t < nt; t++) {
    int buf = t & 1;
    if (t + 1 < nt) {
      LOADA(t + 1);
      STAGEB(buf ^ 1, t + 1);
    }
    short8 af[4], bfg[4];
    #pragma unroll
    for (int i = 0; i < 4; i++)
      af[i] = *(const short8*)((char*)Asm[buf] + arb + i * 1024);
    #pragma unroll
    for (int j = 0; j < 4; j++)
      bfg[j] = *(const short8*)((char*)Bsm[buf] + brb + j * 1024);
    #pragma unroll
    for (int i = 0; i < 4; i++)
      #pragma unroll
      for (int j = 0; j < 4; j++)
        acc[i][j] = mfma16(af[i], bfg[j], acc[i][j]);
    if (t + 1 < nt) WRITEA(buf ^ 1);
    __syncthreads();
  }
  #undef LOADA
  #undef WRITEA
  #undef STAGEB

  float* o = of + (size_t)ksplit * 262144;
  #pragma unroll
  for (int i = 0; i < 4; i++)
    #pragma unroll
    for (int j = 0; j < 4; j++) {
      int n = n0 + wn * 64 + j * 16 + l15;
      #pragma unroll
      for (int r = 0; r < 4; r++) {
        int m = m0 + wm * 64 + i * 16 + l4 * 4 + r;
        o[(size_t)m * 1024 + n] = acc[i][j][r];
      }
    }
}

// ---------------------------------------------------------------------------
// Sum 4 K-split partials + RoPE + scale, write bf16 as (H, BIN, D)
// ---------------------------------------------------------------------------
__global__ __launch_bounds__(256) void rope_kernel(const float* __restrict__ qp,
                                                   const float* __restrict__ cosb,
                                                   const float* __restrict__ sinb,
                                                   unsigned short* __restrict__ qb) {
  int id = blockIdx.x * 256 + threadIdx.x;   // 262144
  int qrow = id >> 10, hd = id & 1023, hh = hd >> 6, d = hd & 63;
  int od = hh * 64 + ((d < 32) ? d + 32 : d - 32);
  float v = 0.f, o = 0.f;
  #pragma unroll
  for (int s4 = 0; s4 < 4; s4++) {
    v += qp[s4 * 262144 + qrow * 1024 + hd];
    o += qp[s4 * 262144 + qrow * 1024 + od];
  }
  if (d < 32) o = -o;
  float c = cosb[qrow * 64 + d];
  float s = sinb[qrow * 64 + d];
  float outv = (v * c + o * s) * 0.18033688011112042f;  // 0.125 * log2(e)
  qb[((size_t)hh * 256 + qrow) * 64 + d] = f2bf(outv);
}

// ---------------------------------------------------------------------------
// Flash attention v7 — 64 keys/barrier + depth-3 counted vmcnt (r19 proven).
// ---------------------------------------------------------------------------
__global__ __launch_bounds__(256) void attn_kernel(const unsigned short* __restrict__ qb,
                                                   const unsigned short* __restrict__ kb,
                                                   const unsigned short* __restrict__ vb,
                                                   const float* __restrict__ Wrp,
                                                   float* __restrict__ part) {
  __shared__ unsigned short Kt[3][4096];   // 2 subtiles x [32 keys][64 d], 8KB
  __shared__ unsigned short Vt[3][4096];   // 2 subtiles x [64 d][32 keys], 8KB

  int bid = blockIdx.x;
  int x = bid & 7, mid = (bid >> 3) & 7, top2 = bid >> 6;
  int g = mid * 8 + x;                 // b*4 + kvh
  int b = g >> 2, kvh = g & 3;
  int split = top2 >> 3;               // 0..1
  int top = top2 & 7;
  int hl = top >> 1, qh = top & 1;
  int h = kvh * 4 + hl;

  int tid = threadIdx.x;
  int w = tid >> 6, l = tid & 63;
  int q31 = l & 31, L = l >> 5;
  int qg = qh * 128 + w * 32 + q31;    // global q row

  const unsigned short* kg = kb + (size_t)(b * 4 + kvh) * 2048 * 64;
  const unsigned short* vg = vb + (size_t)(b * 4 + kvh) * 64 * 2048;

  short8 qf[4];
  #pragma unroll
  for (int c = 0; c < 4; c++)
    qf[c] = *(const short8*)&qb[((size_t)h * 256 + qg) * 64 + c * 16 + L * 8];

  f32x16 Ot[2];
  Ot[0] = (f32x16)(0.f); Ot[1] = (f32x16)(0.f);
  float m = -1e30f, lsum = 0.f;

  int ksrow = tid >> 3, kslot = tid & 7;
  const unsigned short* ksrc = kg + (size_t)ksrow * 64 + ((kslot ^ (ksrow & 7)) * 8);
  int vsrow = tid >> 2, vslot = tid & 3;
  const unsigned short* vsrc = vg + (size_t)vsrow * 2048 + ((vslot ^ ((vsrow >> 1) & 3)) * 8);

  int tb0 = split * 16;                // 64-key step base (16 steps of 64 keys)

  #define STAGE(bufi, tt)                                                       \
    { gl_lds16(ksrc + (size_t)((tt) * 2 + 0) * 2048, (char*)Kt[bufi] + tid * 16);        \
      gl_lds16(ksrc + (size_t)((tt) * 2 + 1) * 2048, (char*)Kt[bufi] + 4096 + tid * 16); \
      gl_lds16(vsrc + ((tt) * 2 + 0) * 32,           (char*)Vt[bufi] + tid * 16);        \
      gl_lds16(vsrc + ((tt) * 2 + 1) * 32,           (char*)Vt[bufi] + 4096 + tid * 16); }

  #define COMPUTE(CB)                                                           \
    _Pragma("unroll")                                                           \
    for (int sub = 0; sub < 2; sub++) {                                         \
      const char* Kb = (const char*)Kt[CB] + sub * 4096;                        \
      const char* Vb = (const char*)Vt[CB] + sub * 4096;                        \
      f32x16 st = (f32x16)(0.f);                                                \
      _Pragma("unroll")                                                         \
      for (int c = 0; c < 4; c++) {                                             \
        int row = q31;                                                          \
        int byt = row * 128 + (((c * 2 + L) ^ (row & 7)) * 16);                 \
        short8 kf = *(const short8*)(Kb + byt);                                 \
        st = mfma32(kf, qf[c], st);                                             \
      }                                                                         \
      float g0 = max3f(st[0], st[1], st[2]);                                    \
      float g1 = max3f(st[3], st[4], st[5]);                                    \
      float g2 = max3f(st[6], st[7], st[8]);                                    \
      float g3 = max3f(st[9], st[10], st[11]);                                  \
      float g4 = max3f(st[12], st[13], st[14]);                                 \
      float mx = fmaxf(max3f(g0, g1, g2), max3f(g3, g4, st[15]));               \
      mx = fmaxf(mx, __shfl_xor(mx, 32));                                       \
      if (!__all(mx <= m + 8.f)) {                                              \
        float mnew = fmaxf(m, mx);                                              \
        float corr = exp2f(m - mnew);                                           \
        lsum *= corr;                                                           \
        _Pragma("unroll")                                                       \
        for (int db = 0; db < 2; db++)                                          \
          _Pragma("unroll")                                                     \
          for (int r = 0; r < 16; r++) Ot[db][r] *= corr;                       \
        m = mnew;                                                               \
      }                                                                         \
      float p[16];                                                              \
      float ls = 0.f;                                                           \
      _Pragma("unroll")                                                         \
      for (int r = 0; r < 16; r++) {                                            \
        p[r] = exp2f(st[r] - m);                                                \
        ls += p[r];                                                             \
      }                                                                         \
      lsum += ls;                                                               \
      unsigned int pw[2][4];                                                    \
      _Pragma("unroll")                                                         \
      for (int kc = 0; kc < 2; kc++) {                                          \
        unsigned int A0 = cvtpk(p[kc * 8 + 0], p[kc * 8 + 1]);                  \
        unsigned int A1 = cvtpk(p[kc * 8 + 2], p[kc * 8 + 3]);                  \
        unsigned int B0 = cvtpk(p[kc * 8 + 4], p[kc * 8 + 5]);                  \
        unsigned int B1 = cvtpk(p[kc * 8 + 6], p[kc * 8 + 7]);                  \
        asm volatile("v_permlane32_swap_b32 %0, %1" : "+v"(A0), "+v"(B0));      \
        asm volatile("v_permlane32_swap_b32 %0, %1" : "+v"(A1), "+v"(B1));      \
        pw[kc][0] = A0; pw[kc][1] = A1; pw[kc][2] = B0; pw[kc][3] = B1;         \
      }                                                                         \
      _Pragma("unroll")                                                         \
      for (int db = 0; db < 2; db++) {                                          \
        int drow = db * 32 + q31;                                               \
        _Pragma("unroll")                                                       \
        for (int kc = 0; kc < 2; kc++) {                                        \
          int byt = drow * 64 + (((kc * 2 + L) ^ ((drow >> 1) & 3)) * 16);      \
          short8 vf = *(const short8*)(Vb + byt);                               \
          short8 pf;                                                            \
          {                                                                     \
            union { short8 s; unsigned int u[4]; } uu;                          \
            uu.u[0] = pw[kc][0]; uu.u[1] = pw[kc][1];                           \
            uu.u[2] = pw[kc][2]; uu.u[3] = pw[kc][3];                           \
            pf = uu.s;                                                          \
          }                                                                     \
          Ot[db] = mfma32(vf, pf, Ot[db]);                                      \
        }                                                                       \
      }                                                                         \
    }

  #define E8                                                                    \
    { asm volatile("s_waitcnt vmcnt(8)" ::: "memory");                          \
      __builtin_amdgcn_s_barrier();                                             \
      __builtin_amdgcn_sched_barrier(0); }

  STAGE(0, tb0 + 0);
  STAGE(1, tb0 + 1);
  asm volatile("s_waitcnt vmcnt(8)" ::: "memory");
  __builtin_amdgcn_s_barrier();
  __builtin_amdgcn_sched_barrier(0);

  #pragma unroll 1
  for (int tb = 0; tb < 12; tb += 3) {
    STAGE(2, tb0 + tb + 2); COMPUTE(0) E8;
    STAGE(0, tb0 + tb + 3); COMPUTE(1) E8;
    STAGE(1, tb0 + tb + 4); COMPUTE(2) E8;
  }
  STAGE(2, tb0 + 14); COMPUTE(0) E8;
  STAGE(0, tb0 + 15); COMPUTE(1) E8;
  COMPUTE(2)
  asm volatile("s_waitcnt vmcnt(0)" ::: "memory");
  __builtin_amdgcn_s_barrier();
  __builtin_amdgcn_sched_barrier(0);
  COMPUTE(0)

  #undef STAGE
  #undef COMPUTE
  #undef E8

  lsum += __shfl_xor(lsum, 32);

  // unnormalized Wrp fold
  float a0 = 0.f, a1 = 0.f;
  #pragma unroll
  for (int db = 0; db < 2; db++)
    #pragma unroll
    for (int rq = 0; rq < 4; rq++) {
      int dbase = db * 32 + rq * 8 + L * 4;
      float4 w0v = *(const float4*)(Wrp + h * 64 + dbase);
      float4 w1v = *(const float4*)(Wrp + 1024 + h * 64 + dbase);
      #pragma unroll
      for (int j = 0; j < 4; j++) {
        float o = Ot[db][rq * 4 + j];
        a0 += o * ((const float*)&w0v)[j];
        a1 += o * ((const float*)&w1v)[j];
      }
    }
  a0 += __shfl_xor(a0, 32);
  a1 += __shfl_xor(a1, 32);

  if (L == 0) {
    size_t base = ((((size_t)(b * 16 + h) * 256 + qg) * 2) + split) * 4;
    float4 r4;
    r4.x = m; r4.y = lsum; r4.z = a0; r4.w = a1;
    *(float4*)&part[base] = r4;
  }
}

// ---------------------------------------------------------------------------
// Combine 2 k-splits + sum heads: out[b,q,c] = br[c] + sum_h num_h/den_h
// ---------------------------------------------------------------------------
__global__ __launch_bounds__(256) void final_kernel(const float* __restrict__ part,
                                                    const float* __restrict__ br,
                                                    float* __restrict__ out) {
  int id = blockIdx.x * 256 + threadIdx.x;   // 8192
  int c = id & 1, q = (id >> 1) & 255, b = id >> 9;
  float s = br[c];
  #pragma unroll
  for (int hh = 0; hh < 16; hh++) {
    size_t base = (((size_t)(b * 16 + hh) * 256 + q) * 2) * 4;
    float4 f0 = *(const float4*)&part[base];
    float4 f1 = *(const float4*)&part[base + 4];
    float mm = fmaxf(f0.x, f1.x);
    float w0 = exp2f(f0.x - mm), w1 = exp2f(f1.x - mm);
    float den = w0 * f0.y + w1 * f1.y;
    float num = (c == 0) ? (w0 * f0.z + w1 * f1.z) : (w0 * f0.w + w1 * f1.w);
    s += num / den;
  }
  out[id] = s;
}

// ---------------------------------------------------------------------------
extern "C" void kernel_launch(void* const* d_in, const int* in_sizes, int n_in,
                              void* d_out, int out_size, void* d_ws, size_t ws_size,
                              hipStream_t stream) {
  const float* h    = (const float*)d_in[0];
  const float* fcos = (const float*)d_in[1];
  const float* fsin = (const float*)d_in[2];
  const float* Wq   = (const float*)d_in[3];
  const float* Wk   = (const float*)d_in[4];
  const float* Wv   = (const float*)d_in[5];
  const float* Wo   = (const float*)d_in[6];
  const float* oq   = (const float*)d_in[7];
  const float* Wr   = (const float*)d_in[8];
  const float* br   = (const float*)d_in[9];
  float* out = (float*)d_out;

  char* ws = (char*)d_ws;
  unsigned short* kbuf = (unsigned short*)(ws);                 // 16 MB (B,KV,K,D) bf16
  unsigned short* vbuf = (unsigned short*)(ws + 16777216);      // 16 MB (B,KV,D,K) bf16
  float* qpart         = (float*)(ws + 33554432);               // 4 MB (4,256,1024)
  unsigned short* qbf  = (unsigned short*)(ws + 37748736);      // 0.5 MB (H,BIN,D)
  float* wpart         = (float*)(ws + 38273024);               // 128 KB
  float* Wrp           = (float*)(ws + 38404096);               // 8 KB
  float* apart         = (float*)(ws + 38412288);               // 2 MB (B,H,BIN,2,4)
  unsigned short* wqb  = (unsigned short*)(ws + 42606592);      // 2 MB (1024,1024)
  unsigned short* wkvb = (unsigned short*)(ws + 44703744);      // 1 MB (512,1024)
  unsigned short* vrm  = (unsigned short*)(ws + 45752320);      // 16 MB (B,KV,K,D) bf16

  cvtB_kernel<<<dim3(1536), dim3(256), 0, stream>>>(Wq, Wk, Wv, wqb, wkvb);
  wrp_partial<<<dim3(16), dim3(256), 0, stream>>>(Wr, Wo, wpart);
  wrp_reduce<<<dim3(8), dim3(256), 0, stream>>>(wpart, Wrp);
  gemm_q<<<dim3(64), dim3(256), 0, stream>>>(oq, wqb, qpart);
  rope_kernel<<<dim3(1024), dim3(256), 0, stream>>>(qpart, fcos, fsin, qbf);
  gemm_kv<<<dim3(256), dim3(512), 0, stream>>>(h, wkvb, kbuf, vrm);
  vtr_kernel<<<dim3(2048), dim3(256), 0, stream>>>(vrm, vbuf);
  attn_kernel<<<dim3(1024), dim3(256), 0, stream>>>(qbf, kbuf, vbuf, Wrp, apart);
  final_kernel<<<dim3(32), dim3(256), 0, stream>>>(apart, br, out);
}